// Round 1
// baseline (1079.624 us; speedup 1.0000x reference)
//
#include <hip/hip_runtime.h>
#include <stdint.h>
#include <math.h>

#define NTOK 4096
#define DIM  1024
#define NEXP 64
#define KSEL 6
#define FF   1408
#define FF2  2816
#define DFFC 4096
#define CAPE 768

typedef __bf16 bf16x8 __attribute__((ext_vector_type(8)));
typedef float  f32x4  __attribute__((ext_vector_type(4)));

__device__ __forceinline__ float bf2f(uint32_t h) {
  union { uint32_t u; float f; } v; v.u = h << 16; return v.f;
}
__device__ __forceinline__ uint16_t f2bf(float f) {
  union { float f; uint32_t u; } v; v.f = f;
  return (uint16_t)((v.u + 0x7fffu + ((v.u >> 16) & 1u)) >> 16);
}
__device__ __forceinline__ void load_lds16(const void* g, void* l) {
  __builtin_amdgcn_global_load_lds((const __attribute__((address_space(1))) void*)g,
                                   (__attribute__((address_space(3))) void*)l, 16, 0, 0);
}

// ---------------- cast f32 -> bf16 (vectorized) ----------------
__global__ __launch_bounds__(256) void cast_f32_bf16(const float* __restrict__ in,
                                                     uint16_t* __restrict__ out, int n4) {
  int i = blockIdx.x * 256 + threadIdx.x;
  if (i >= n4) return;
  float4 v = ((const float4*)in)[i];
  ushort4 o;
  o.x = f2bf(v.x); o.y = f2bf(v.y); o.z = f2bf(v.z); o.w = f2bf(v.w);
  ((ushort4*)out)[i] = o;
}

// ---------------- transpose + cast: in [z][R][C] f32 -> out [z][C'][R] bf16 ----------------
template<bool REMAP>
__global__ __launch_bounds__(256) void transpose_cast(const float* __restrict__ in,
                                                      uint16_t* __restrict__ out,
                                                      int R, int C, int Fh) {
  const int e = blockIdx.z;
  const int c0 = blockIdx.x * 64, r0 = blockIdx.y * 64;
  __shared__ float t[64][65];
  const float* ine = in + (size_t)e * R * C;
  uint16_t* oute = out + (size_t)e * R * C;
  const int lane = threadIdx.x & 63, grp = threadIdx.x >> 6;
#pragma unroll
  for (int i = 0; i < 16; i++) {
    int r = i * 4 + grp;
    t[r][lane] = ine[(size_t)(r0 + r) * C + c0 + lane];
  }
  __syncthreads();
#pragma unroll
  for (int i = 0; i < 16; i++) {
    int cl = i * 4 + grp;
    int c = c0 + cl;
    int orow;
    if (REMAP) {
      orow = (c < Fh) ? (((c >> 4) << 5) + (c & 15))
                      : ((((c - Fh) >> 4) << 5) + 16 + (c & 15));
    } else {
      orow = c;
    }
    oute[(size_t)orow * R + r0 + lane] = f2bf(t[lane][cl]);
  }
}

// ---------------- router: logits, top-6, gating, z partial ----------------
__global__ __launch_bounds__(256) void router_kernel(const float* __restrict__ x,
                                                     const float* __restrict__ rw,
                                                     int* __restrict__ topk,
                                                     uint16_t* __restrict__ gating,
                                                     float* __restrict__ tokz) {
  __shared__ float hs[16 * DIM];
  __shared__ float lg[16][NEXP];
  const int tid = threadIdx.x;
  const int t0 = blockIdx.x * 16;
  const float4* xin = (const float4*)(x + (size_t)t0 * DIM);
  float4* hs4 = (float4*)hs;
  for (int i = tid; i < 16 * DIM / 4; i += 256) hs4[i] = xin[i];
  __syncthreads();
  const int e = tid >> 2, q = tid & 3;
  float part[16];
#pragma unroll
  for (int tt = 0; tt < 16; tt++) part[tt] = 0.f;
  const float4* rw4 = (const float4*)(rw + (size_t)e * DIM + q * 256);
  for (int i = 0; i < 64; i++) {
    float4 w = rw4[i];
#pragma unroll
    for (int tt = 0; tt < 16; tt++) {
      float4 h = *(const float4*)(hs + tt * DIM + q * 256 + i * 4);
      part[tt] += h.x * w.x + h.y * w.y + h.z * w.z + h.w * w.w;
    }
  }
#pragma unroll
  for (int tt = 0; tt < 16; tt++) {
    float v = part[tt];
    v += __shfl_xor(v, 1);
    v += __shfl_xor(v, 2);
    if (q == 0) lg[tt][e] = v;
  }
  __syncthreads();
  const int wid = tid >> 6, lane = tid & 63;
  for (int ti = 0; ti < 4; ti++) {
    int tt = wid * 4 + ti;
    float v = lg[tt][lane];
    float z = v * v;
#pragma unroll
    for (int off = 32; off; off >>= 1) z += __shfl_xor(z, off);
    float bv[KSEL]; int bi[KSEL];
#pragma unroll
    for (int s = 0; s < KSEL; s++) {
      float m = v; int mi = lane;
#pragma unroll
      for (int off = 32; off; off >>= 1) {
        float om = __shfl_xor(m, off); int oi = __shfl_xor(mi, off);
        if (om > m || (om == m && oi < mi)) { m = om; mi = oi; }
      }
      bv[s] = m; bi[s] = mi;
      if (lane == mi) v = -3.0e38f;
    }
    if (lane == 0) {
      int t = t0 + tt;
      tokz[t] = z;
      float mx = bv[0];
      float ex[KSEL], sum = 0.f;
#pragma unroll
      for (int s = 0; s < KSEL; s++) { ex[s] = expf(bv[s] - mx); sum += ex[s]; }
      float inv = 1.f / sum;
#pragma unroll
      for (int s = 0; s < KSEL; s++) {
        topk[t * KSEL + s] = bi[s];
        gating[t * KSEL + s] = f2bf(ex[s] * inv);
      }
    }
  }
}

// ---------------- z_loss reduce ----------------
__global__ __launch_bounds__(256) void zred_kernel(const float* __restrict__ tz,
                                                   float* __restrict__ out) {
  __shared__ float s[256];
  float a = 0.f;
  for (int i = threadIdx.x; i < NTOK; i += 256) a += tz[i];
  s[threadIdx.x] = a; __syncthreads();
  for (int st = 128; st; st >>= 1) {
    if (threadIdx.x < (unsigned)st) s[threadIdx.x] += s[threadIdx.x + st];
    __syncthreads();
  }
  if (threadIdx.x == 0) out[0] = s[0] * (1e-6f / ((float)NTOK * (float)NEXP));
}

// ---------------- dispatch: stable rank within expert ----------------
__global__ __launch_bounds__(64) void dispatch_kernel(const int* __restrict__ topk,
                                                      int* __restrict__ dest,
                                                      int* __restrict__ invmap,
                                                      int* __restrict__ counts) {
  const int e = blockIdx.x;
  const int lane = threadIdx.x;
  int base = 0;
  for (int it = 0; it < (NTOK * KSEL) / 64; it++) {
    int p = it * 64 + lane;
    int ex = topk[p];
    bool m = (ex == e);
    unsigned long long mask = __ballot(m);
    if (m) {
      int intra = base + __popcll(mask & ((1ull << lane) - 1ull));
      if (intra < CAPE) {
        dest[p] = e * CAPE + intra;
        invmap[e * CAPE + intra] = p / KSEL;
      } else {
        dest[p] = -1;
      }
    }
    base += __popcll(mask);
  }
  if (lane == 0) counts[e] = base < CAPE ? base : CAPE;
}

// ---------------- GEMM: C[M,N] = A[M,K] * B^T[N,K], bf16 in, f32 acc ----------------
// EPI: 0 = store bf16, 1 = store f32, 2 = SwiGLU-pair store (interleaved-16 cols) -> bf16
#define BM 128
#define BN 128
#define BKK 64

template<int EPI, bool IND>
__global__ __launch_bounds__(256, 2) void gemm_bt(const uint16_t* __restrict__ A,
                                                  const uint16_t* __restrict__ B,
                                                  void* __restrict__ C,
                                                  const int* __restrict__ invmap,
                                                  const int* __restrict__ counts,
                                                  int K, int lda, int ldb, int ldc,
                                                  long long strideA, long long strideB,
                                                  long long strideC, int grouped) {
  const int e = blockIdx.z;
  int cnt = 1 << 30;
  if (grouped) {
    cnt = counts[e];
    if ((int)(blockIdx.y * BM) >= cnt) return;
  }
  const int bm0 = blockIdx.y * BM, bn0 = blockIdx.x * BN;
  const uint16_t* Ab = A + (size_t)e * strideA;
  const uint16_t* Bb = B + (size_t)e * strideB;
  __shared__ uint16_t sA[BM * BKK];
  __shared__ uint16_t sB[BN * BKK];
  const int tid = threadIdx.x, wid = tid >> 6, lane = tid & 63;
  const int colk = (tid & 7) * 8;
  const uint16_t* ap[4];
  const uint16_t* bp[4];
#pragma unroll
  for (int i = 0; i < 4; i++) {
    int row = i * 32 + (tid >> 3);
    int ar = bm0 + row;
    if constexpr (IND) {
      int cr = ar < cnt ? ar : (cnt - 1);
      ar = invmap[e * CAPE + cr];
    }
    ap[i] = Ab + (size_t)ar * lda + colk;
    bp[i] = Bb + (size_t)(bn0 + row) * ldb + colk;
  }
  f32x4 zero = {0.f, 0.f, 0.f, 0.f};
  f32x4 acc[4][4];
#pragma unroll
  for (int i = 0; i < 4; i++)
#pragma unroll
    for (int j = 0; j < 4; j++) acc[i][j] = zero;
  const int wm = wid >> 1, wn = wid & 1;
  for (int k0 = 0; k0 < K; k0 += BKK) {
#pragma unroll
    for (int i = 0; i < 4; i++) {
      load_lds16(ap[i], sA + i * 2048 + wid * 512);
      load_lds16(bp[i], sB + i * 2048 + wid * 512);
      ap[i] += BKK; bp[i] += BKK;
    }
    __syncthreads();
#pragma unroll
    for (int ks = 0; ks < 2; ks++) {
      const int kb = ks * 32 + (lane >> 4) * 8;
      bf16x8 af[4], bfr[4];
#pragma unroll
      for (int f = 0; f < 4; f++)
        af[f] = *(const bf16x8*)(sA + (wm * 64 + f * 16 + (lane & 15)) * BKK + kb);
#pragma unroll
      for (int f = 0; f < 4; f++)
        bfr[f] = *(const bf16x8*)(sB + (wn * 64 + f * 16 + (lane & 15)) * BKK + kb);
#pragma unroll
      for (int fm = 0; fm < 4; fm++)
#pragma unroll
        for (int fn = 0; fn < 4; fn++)
          acc[fm][fn] = __builtin_amdgcn_mfma_f32_16x16x32_bf16(af[fm], bfr[fn],
                                                                acc[fm][fn], 0, 0, 0);
    }
    __syncthreads();
  }
  const int lr = (lane >> 4) * 4, lc = lane & 15;
  if constexpr (EPI == 2) {
    uint16_t* outp = (uint16_t*)C + (size_t)e * strideC;
#pragma unroll
    for (int fm = 0; fm < 4; fm++) {
#pragma unroll
      for (int fp = 0; fp < 2; fp++) {
        f32x4 g = acc[fm][2 * fp], u = acc[fm][2 * fp + 1];
        int fcol = (bn0 >> 1) + wn * 32 + fp * 16 + lc;
#pragma unroll
        for (int j = 0; j < 4; j++) {
          int r = bm0 + wm * 64 + fm * 16 + lr + j;
          float gv = g[j];
          float sv = (gv / (1.f + expf(-gv))) * u[j];
          outp[(size_t)r * ldc + fcol] = f2bf(sv);
        }
      }
    }
  } else if constexpr (EPI == 1) {
    float* outp = (float*)C + (size_t)e * strideC;
#pragma unroll
    for (int fm = 0; fm < 4; fm++)
#pragma unroll
      for (int fn = 0; fn < 4; fn++) {
        int col = bn0 + wn * 64 + fn * 16 + lc;
#pragma unroll
        for (int j = 0; j < 4; j++) {
          int r = bm0 + wm * 64 + fm * 16 + lr + j;
          outp[(size_t)r * ldc + col] = acc[fm][fn][j];
        }
      }
  } else {
    uint16_t* outp = (uint16_t*)C + (size_t)e * strideC;
#pragma unroll
    for (int fm = 0; fm < 4; fm++)
#pragma unroll
      for (int fn = 0; fn < 4; fn++) {
        int col = bn0 + wn * 64 + fn * 16 + lc;
#pragma unroll
        for (int j = 0; j < 4; j++) {
          int r = bm0 + wm * 64 + fm * 16 + lr + j;
          outp[(size_t)r * ldc + col] = f2bf(acc[fm][fn][j]);
        }
      }
  }
}

// ---------------- elementwise SwiGLU for shared expert ----------------
__global__ __launch_bounds__(256) void swiglu_mul(const uint16_t* __restrict__ g,
                                                  const uint16_t* __restrict__ u,
                                                  uint16_t* __restrict__ s, int n8) {
  int i = blockIdx.x * 256 + threadIdx.x;
  if (i >= n8) return;
  uint4 gv = ((const uint4*)g)[i], uv = ((const uint4*)u)[i];
  uint32_t* gp = (uint32_t*)&gv;
  uint32_t* up = (uint32_t*)&uv;
  uint4 ov;
  uint32_t* op = (uint32_t*)&ov;
#pragma unroll
  for (int j = 0; j < 4; j++) {
    float g0 = bf2f(gp[j] & 0xffffu), g1 = bf2f(gp[j] >> 16);
    float u0 = bf2f(up[j] & 0xffffu), u1 = bf2f(up[j] >> 16);
    float s0 = g0 / (1.f + expf(-g0)) * u0;
    float s1 = g1 / (1.f + expf(-g1)) * u1;
    op[j] = (uint32_t)f2bf(s0) | ((uint32_t)f2bf(s1) << 16);
  }
  ((uint4*)s)[i] = ov;
}

// ---------------- combine ----------------
__global__ __launch_bounds__(256) void combine_kernel(const float* __restrict__ shout,
                                                      const uint16_t* __restrict__ eout,
                                                      const int* __restrict__ dest,
                                                      const uint16_t* __restrict__ gating,
                                                      float* __restrict__ out) {
  const int t = blockIdx.x;
  const int d0 = threadIdx.x * 4;
  float4 sh = *(const float4*)(shout + (size_t)t * DIM + d0);
  float rx = 0.f, ry = 0.f, rz = 0.f, rw = 0.f;
#pragma unroll
  for (int k = 0; k < KSEL; k++) {
    int dp = dest[t * KSEL + k];
    if (dp >= 0) {
      float gw = bf2f(gating[t * KSEL + k]);
      ushort4 ev = *(const ushort4*)(eout + (size_t)dp * DIM + d0);
      rx += gw * bf2f(ev.x);
      ry += gw * bf2f(ev.y);
      rz += gw * bf2f(ev.z);
      rw += gw * bf2f(ev.w);
    }
  }
  float4 o;
  o.x = (sh.x + rx) * 0.5f;
  o.y = (sh.y + ry) * 0.5f;
  o.z = (sh.z + rz) * 0.5f;
  o.w = (sh.w + rw) * 0.5f;
  *(float4*)(out + (size_t)t * DIM + d0) = o;
}

extern "C" void kernel_launch(void* const* d_in, const int* in_sizes, int n_in,
                              void* d_out, int out_size, void* d_ws, size_t ws_size,
                              hipStream_t stream) {
  (void)in_sizes; (void)n_in; (void)out_size; (void)ws_size;
  const float* x   = (const float*)d_in[0];
  const float* rw  = (const float*)d_in[1];
  const float* w12 = (const float*)d_in[2];
  const float* w3  = (const float*)d_in[3];
  const float* gw  = (const float*)d_in[4];
  const float* uw  = (const float*)d_in[5];
  const float* dw  = (const float*)d_in[6];
  float* out = (float*)d_out;

  char* ws = (char*)d_ws;
  size_t off = 0;
  auto alloc = [&](size_t sz) -> void* {
    void* p = ws + off;
    off += (sz + 255) & ~(size_t)255;
    return p;
  };
  uint16_t* W12T  = (uint16_t*)alloc((size_t)NEXP * FF2 * DIM * 2);   // [E][2816(il)][1024]
  uint16_t* W3T   = (uint16_t*)alloc((size_t)NEXP * DIM * FF * 2);    // [E][1024][1408]
  uint16_t* GATET = (uint16_t*)alloc((size_t)DFFC * DIM * 2);
  uint16_t* UPT   = (uint16_t*)alloc((size_t)DFFC * DIM * 2);
  uint16_t* DOWNT = (uint16_t*)alloc((size_t)DIM * DFFC * 2);
  uint16_t* HB    = (uint16_t*)alloc((size_t)NTOK * DIM * 2);
  char* REGION    = (char*)alloc((size_t)NEXP * CAPE * FF * 2);       // act aliases g,u,s1
  uint16_t* GBUF  = (uint16_t*)REGION;
  uint16_t* UBUF  = (uint16_t*)(REGION + (size_t)NTOK * DFFC * 2);
  uint16_t* S1    = (uint16_t*)(REGION + (size_t)NTOK * DFFC * 4);
  uint16_t* ACT   = (uint16_t*)REGION;
  uint16_t* EOUT  = (uint16_t*)alloc((size_t)NEXP * CAPE * DIM * 2);
  float* SHOUT    = (float*)alloc((size_t)NTOK * DIM * 4);
  int* TOPKB      = (int*)alloc((size_t)NTOK * KSEL * 4);
  uint16_t* GATING= (uint16_t*)alloc((size_t)NTOK * KSEL * 2);
  int* DEST       = (int*)alloc((size_t)NTOK * KSEL * 4);
  int* INVMAP     = (int*)alloc((size_t)NEXP * CAPE * 4);
  int* COUNTS     = (int*)alloc((size_t)NEXP * 4);
  float* TOKZ     = (float*)alloc((size_t)NTOK * 4);

  // weight conversion / transposition
  transpose_cast<true><<<dim3(FF2 / 64, DIM / 64, NEXP), 256, 0, stream>>>(w12, W12T, DIM, FF2, FF);
  transpose_cast<false><<<dim3(DIM / 64, FF / 64, NEXP), 256, 0, stream>>>(w3, W3T, FF, DIM, 0);
  cast_f32_bf16<<<4096, 256, 0, stream>>>(gw, GATET, (DFFC * DIM) / 4);
  cast_f32_bf16<<<4096, 256, 0, stream>>>(uw, UPT, (DFFC * DIM) / 4);
  cast_f32_bf16<<<4096, 256, 0, stream>>>(dw, DOWNT, (DIM * DFFC) / 4);
  cast_f32_bf16<<<4096, 256, 0, stream>>>(x, HB, (NTOK * DIM) / 4);

  // router / dispatch / z-loss
  router_kernel<<<NTOK / 16, 256, 0, stream>>>(x, rw, TOPKB, GATING, TOKZ);
  dispatch_kernel<<<NEXP, 64, 0, stream>>>(TOPKB, DEST, INVMAP, COUNTS);
  zred_kernel<<<1, 256, 0, stream>>>(TOKZ, out + (size_t)NTOK * DIM);

  // shared expert
  gemm_bt<0, false><<<dim3(DFFC / BN, NTOK / BM, 1), 256, 0, stream>>>(
      HB, GATET, GBUF, nullptr, nullptr, DIM, DIM, DIM, DFFC, 0, 0, 0, 0);
  gemm_bt<0, false><<<dim3(DFFC / BN, NTOK / BM, 1), 256, 0, stream>>>(
      HB, UPT, UBUF, nullptr, nullptr, DIM, DIM, DIM, DFFC, 0, 0, 0, 0);
  swiglu_mul<<<(NTOK * DFFC / 8) / 256, 256, 0, stream>>>(GBUF, UBUF, S1, NTOK * DFFC / 8);
  gemm_bt<1, false><<<dim3(DIM / BN, NTOK / BM, 1), 256, 0, stream>>>(
      S1, DOWNT, SHOUT, nullptr, nullptr, DFFC, DFFC, DFFC, DIM, 0, 0, 0, 0);

  // routed experts (grouped)
  gemm_bt<2, true><<<dim3(FF2 / BN, CAPE / BM, NEXP), 256, 0, stream>>>(
      HB, W12T, ACT, INVMAP, COUNTS, DIM, DIM, DIM, FF,
      0, (long long)FF2 * DIM, (long long)CAPE * FF, 1);
  gemm_bt<0, false><<<dim3(DIM / BN, CAPE / BM, NEXP), 256, 0, stream>>>(
      ACT, W3T, EOUT, nullptr, COUNTS, FF, FF, FF, DIM,
      (long long)CAPE * FF, (long long)DIM * FF, (long long)CAPE * DIM, 1);

  // combine
  combine_kernel<<<NTOK, 256, 0, stream>>>(SHOUT, EOUT, DEST, GATING, out);
}